// Round 6
// baseline (405.077 us; speedup 1.0000x reference)
//
#include <hip/hip_runtime.h>
#include <stdint.h>

// Problem constants
#define B_    32
#define L_    512
#define DIN_  768
#define H_    16
#define DH_   48
#define DOUT_ 768
#define NHEADS (B_ * H_)          // 512
#define HEADELEMS (L_ * DH_)      // 24576 elems per head

typedef short bf16x8 __attribute__((ext_vector_type(8)));  // 8 bf16 (4 VGPRs)
typedef float f32x4  __attribute__((ext_vector_type(4)));  // MFMA accumulator

// ---------------------------------------------------------------------------
// bf16 helpers (manual RNE)
// ---------------------------------------------------------------------------
__device__ __forceinline__ uint16_t f2bf(float f) {
  uint32_t u = __float_as_uint(f);
  u += 0x7fffu + ((u >> 16) & 1u);
  return (uint16_t)(u >> 16);
}
__device__ __forceinline__ uint32_t pack2bf(float lo, float hi) {
  uint32_t a = __float_as_uint(lo);
  a += 0x7fffu + ((a >> 16) & 1u);
  uint32_t b = __float_as_uint(hi);
  b += 0x7fffu + ((b >> 16) & 1u);
  return (a >> 16) | (b & 0xffff0000u);
}
// async global->LDS, 16B per lane
__device__ __forceinline__ void gload_lds16(const void* g, void* l) {
  __builtin_amdgcn_global_load_lds(
      (const __attribute__((address_space(1))) uint32_t*)g,
      (__attribute__((address_space(3))) uint32_t*)l, 16, 0, 0);
}
// bf16x8 fragment from LDS at 8B-aligned address
__device__ __forceinline__ bf16x8 lds_frag8(const uint16_t* p) {
  union { uint2 u[2]; bf16x8 v; } x;
  x.u[0] = *(const uint2*)(p);
  x.u[1] = *(const uint2*)(p + 4);
  return x.v;
}

// ---------------------------------------------------------------------------
// Kernel 0: canonicalize Q_len / V_len (int64-vs-int32 autodetect).
// ---------------------------------------------------------------------------
__global__ void lens_kernel(const int* __restrict__ qlen_raw,
                            const int* __restrict__ vlen_raw,
                            int* __restrict__ lens) {
  __shared__ int is64[2];
  int t = threadIdx.x;
  if (t < 2) {
    const int* src = (t == 0) ? qlen_raw : vlen_raw;
    int o = 0;
    for (int i = 0; i < 16; ++i) o |= src[2 * i + 1];
    is64[t] = (o == 0) ? 1 : 0;
  }
  __syncthreads();
  int which = t >> 5;
  int i = t & 31;
  const int* src = which ? vlen_raw : qlen_raw;
  lens[t] = is64[which] ? src[2 * i] : src[i];
}

// ---------------------------------------------------------------------------
// Kernel 1: W transpose+convert.  Wt[z][n][k] = bf16(W_z[k][n]).
// ---------------------------------------------------------------------------
__global__ void wconv_kernel(const float* __restrict__ WQ,
                             const float* __restrict__ WK,
                             const float* __restrict__ WV,
                             uint16_t* __restrict__ Wt) {
  const int z = blockIdx.z;
  const float* W = (z == 0) ? WQ : (z == 1) ? WK : WV;
  uint16_t* dst = Wt + (size_t)z * DIN_ * DOUT_;
  const int n  = blockIdx.x * 256 + threadIdx.x;
  const int k4 = blockIdx.y * 4;
  float f0 = W[(size_t)(k4 + 0) * DOUT_ + n];
  float f1 = W[(size_t)(k4 + 1) * DOUT_ + n];
  float f2 = W[(size_t)(k4 + 2) * DOUT_ + n];
  float f3 = W[(size_t)(k4 + 3) * DOUT_ + n];
  uint2 p;
  p.x = pack2bf(f0, f1);
  p.y = pack2bf(f2, f3);
  *(uint2*)&dst[(size_t)n * DIN_ + k4] = p;
}

// ---------------------------------------------------------------------------
// Kernel 2: MFMA projection GEMM v4 — BK=64 (half the barriers) + XOR-swizzled
// LDS (kills the round-5 1.06e7 bank-conflict cycles).
// 128x128 tile, 512 threads (8 waves), wave tile 32m x 64n (32 AGPR acc).
// LDS chunk layout: 16B chunk j of row r lives at physical pos j^(r&7);
// applied at A-store, B-gload-src, and fragment reads symmetrically.
// ---------------------------------------------------------------------------
__global__ __launch_bounds__(512, 6) void mfma_proj(
    const float* __restrict__ Xq, const float* __restrict__ Xk,
    const float* __restrict__ Xv, const uint16_t* __restrict__ Wt,
    uint16_t* __restrict__ qh, uint16_t* __restrict__ kh,
    uint16_t* __restrict__ vh) {
  const int z = blockIdx.z;
  const float* X = (z == 0) ? Xq : (z == 1) ? Xk : Xv;
  uint16_t* dst  = (z == 0) ? qh : (z == 1) ? kh : vh;
  const uint16_t* W = Wt + (size_t)z * DIN_ * DOUT_;   // [n][k] bf16

  __shared__ uint16_t As[128][64];   // 16 KB [m][k], swizzled chunks
  __shared__ uint16_t Bs[128][64];   // 16 KB [n][k], swizzled chunks

  const int t  = threadIdx.x;
  const int m0 = blockIdx.x * 128;
  const int n0 = blockIdx.y * 128;

  // A staging: 4 threads/row, each owns logical chunks ja0, ja0+1 (16 elems)
  const int ra  = t >> 2;
  const int ja0 = (t & 3) * 2;
  const float* aptr = X + (size_t)(m0 + ra) * DIN_ + ja0 * 8;
  const int sa0 = (ja0 ^ (ra & 7)) * 8;        // swizzled elem offsets
  const int sa1 = ((ja0 + 1) ^ (ra & 7)) * 8;

  // B staging: 2 chunks per thread; dst LDS-linear (forced by gload), source
  // chunk swizzled so logical chunk j of row r lands at physical j^(r&7).
  const int c0b = t;          // chunk ids
  const int c1b = t + 512;
  const int r0b = c0b >> 3, j0b = c0b & 7, s0b = (j0b ^ (r0b & 7)) * 8;
  const int r1b = c1b >> 3, j1b = c1b & 7, s1b = (j1b ^ (r1b & 7)) * 8;
  const uint16_t* bsrc0 = W + (size_t)(n0 + r0b) * DIN_ + s0b;
  const uint16_t* bsrc1 = W + (size_t)(n0 + r1b) * DIN_ + s1b;
  char* ldsB = (char*)(&Bs[0][0]);

  const int w = t >> 6, lane = t & 63;
  const int wm = (w & 3) * 32, wn = (w >> 2) * 64;
  const int fr = lane & 15;
  const int quad = lane >> 4;

  f32x4 acc[2][4];
#pragma unroll
  for (int i = 0; i < 2; ++i)
#pragma unroll
    for (int j = 0; j < 4; ++j) acc[i][j] = f32x4{0.f, 0.f, 0.f, 0.f};

  for (int kt = 0; kt < DIN_ / 64; ++kt) {
    const int k0 = kt * 64;
    gload_lds16(bsrc0 + k0, ldsB + c0b * 16);
    gload_lds16(bsrc1 + k0, ldsB + c1b * 16);
    float4 x0 = *(const float4*)(aptr + k0);
    float4 x1 = *(const float4*)(aptr + k0 + 4);
    float4 x2 = *(const float4*)(aptr + k0 + 8);
    float4 x3 = *(const float4*)(aptr + k0 + 12);
    uint4 pA, pB;
    pA.x = pack2bf(x0.x, x0.y); pA.y = pack2bf(x0.z, x0.w);
    pA.z = pack2bf(x1.x, x1.y); pA.w = pack2bf(x1.z, x1.w);
    pB.x = pack2bf(x2.x, x2.y); pB.y = pack2bf(x2.z, x2.w);
    pB.z = pack2bf(x3.x, x3.y); pB.w = pack2bf(x3.z, x3.w);
    *(uint4*)&As[ra][sa0] = pA;
    *(uint4*)&As[ra][sa1] = pB;
    __syncthreads();   // drains vmcnt (B) + lgkm (A)

#pragma unroll
    for (int ks = 0; ks < 2; ++ks) {
      bf16x8 af[2], bfr[4];
#pragma unroll
      for (int i = 0; i < 2; ++i) {
        const int row = wm + i * 16 + fr;
        af[i] = *(const bf16x8*)&As[row][((4 * ks + quad) ^ (row & 7)) * 8];
      }
#pragma unroll
      for (int j = 0; j < 4; ++j) {
        const int row = wn + j * 16 + fr;
        bfr[j] = *(const bf16x8*)&Bs[row][((4 * ks + quad) ^ (row & 7)) * 8];
      }
#pragma unroll
      for (int mt = 0; mt < 2; ++mt)
#pragma unroll
        for (int nt = 0; nt < 4; ++nt)
          acc[mt][nt] = __builtin_amdgcn_mfma_f32_16x16x32_bf16(
              af[mt], bfr[nt], acc[mt][nt], 0, 0, 0);
    }
    __syncthreads();
  }

  // epilogue: D[row=quad*4+r][col=fr] -> head-major bf16
#pragma unroll
  for (int mt = 0; mt < 2; ++mt) {
#pragma unroll
    for (int r = 0; r < 4; ++r) {
      const int m  = m0 + wm + mt * 16 + quad * 4 + r;
      const int bb = m >> 9;
      const int l  = m & 511;
#pragma unroll
      for (int nt = 0; nt < 4; ++nt) {
        const int n = n0 + wn + nt * 16 + fr;
        const int h = n / DH_;
        const int d = n - h * DH_;
        dst[(((size_t)bb * H_ + h) * L_ + l) * DH_ + d] = f2bf(acc[mt][nt][r]);
      }
    }
  }
}

// ---------------------------------------------------------------------------
// Kernel 3: MFMA attention v5 — max-free softmax, 3 blocks/CU, 3 barriers/iter.
// L-combine via LDS atomicAdd (ds_add_f32) removes the cmb stage+barrier;
// 1/L applied inline in the V-scale loop.
// ---------------------------------------------------------------------------
__global__ __launch_bounds__(256, 3) void attn_mfma(
    const uint16_t* __restrict__ qh, const uint16_t* __restrict__ kh,
    const uint16_t* __restrict__ vh, const int* __restrict__ lens,
    float* __restrict__ out) {
  const int bh = blockIdx.x;
  const int b  = bh >> 4;
  const int h  = bh & 15;
  const int t    = threadIdx.x;
  const int w    = t >> 6;
  const int lane = t & 63;
  const int l15  = lane & 15;
  const int quad = lane >> 4;

  const int qlen = lens[b];
  const int vlen = lens[32 + b];
  const bool deg = (vlen == 0);
  const size_t head = (size_t)bh * HEADELEMS;

  __shared__ uint16_t Pt[4][128][36];  // 36864 B  [wave][k_loc][q_loc] (unnorm e)
  __shared__ uint16_t Vt[48][36];      //  3456 B  [d][q_loc] raw -> scaled
  __shared__ float    Ls[32];          //   128 B  row sums (atomic)

  const uint16_t* qbase = qh + head;
  const uint16_t* kbase = kh + head;
  const uint16_t* vbase = vh + head;

  f32x4 Oacc[8][3];
#pragma unroll
  for (int i = 0; i < 8; ++i)
#pragma unroll
    for (int dt = 0; dt < 3; ++dt) Oacc[i][dt] = f32x4{0.f, 0.f, 0.f, 0.f};

  const float scale = 0.14433756729740643f;  // 1/sqrt(48)
  const int vq  = t & 31;
  const int vd4 = t >> 5;

  if (t < 32) Ls[t] = 0.0f;

  for (int g = 0; g < 16; ++g) {
    const int q0 = g * 32;
    const int lim = q0 + 31 - 16 * w;   // tile i active iff 64*i <= lim

    __syncthreads();   // B0: prev-iter PV done with Pt/Vt; Ls zero visible

    // ---- stage Vt[d][q_loc] raw bf16 ----
    {
      uint2 u = *(const uint2*)(vbase + (size_t)(q0 + vq) * DH_ + vd4 * 4);
      Vt[vd4 * 4 + 0][vq] = (uint16_t)(u.x);
      Vt[vd4 * 4 + 1][vq] = (uint16_t)(u.x >> 16);
      Vt[vd4 * 4 + 2][vq] = (uint16_t)(u.y);
      Vt[vd4 * 4 + 3][vq] = (uint16_t)(u.y >> 16);
      if (t < 128) {
        int d4b = 8 + (t >> 5);
        uint2 v = *(const uint2*)(vbase + (size_t)(q0 + vq) * DH_ + d4b * 4);
        Vt[d4b * 4 + 0][vq] = (uint16_t)(v.x);
        Vt[d4b * 4 + 1][vq] = (uint16_t)(v.x >> 16);
        Vt[d4b * 4 + 2][vq] = (uint16_t)(v.y);
        Vt[d4b * 4 + 3][vq] = (uint16_t)(v.y >> 16);
      }
    }

    // ---- Q A-fragments (2 m-tiles x 2 K-steps), d 48..63 zero-padded ----
    bf16x8 aq[2][2];
#pragma unroll
    for (int mt = 0; mt < 2; ++mt) {
      const uint16_t* qp = qbase + (size_t)(q0 + mt * 16 + l15) * DH_;
      aq[mt][0] = *(const bf16x8*)(qp + quad * 8);
      bf16x8 zz = {0, 0, 0, 0, 0, 0, 0, 0};
      aq[mt][1] = zz;
      if (quad < 2) aq[mt][1] = *(const bf16x8*)(qp + 32 + quad * 8);
    }

    // ---- single pass: S-MFMA -> e=exp(s) -> row-sum + pack to Pt ----
    float lrun[2][4];
#pragma unroll
    for (int mt = 0; mt < 2; ++mt)
#pragma unroll
      for (int r = 0; r < 4; ++r) lrun[mt][r] = 0.0f;

#pragma unroll
    for (int i = 0; i < 8; ++i) {
      if (64 * i > lim) continue;   // wave-uniform causal tile skip
      const int kb = 64 * i + 16 * w;
      f32x4 s0 = {0.f, 0.f, 0.f, 0.f};
      f32x4 s1 = {0.f, 0.f, 0.f, 0.f};
      if (!deg) {
        const uint16_t* kp = kbase + (size_t)(kb + l15) * DH_;
        bf16x8 bk0 = *(const bf16x8*)(kp + quad * 8);
        bf16x8 bk1 = {0, 0, 0, 0, 0, 0, 0, 0};
        if (quad < 2) bk1 = *(const bf16x8*)(kp + 32 + quad * 8);
        s0 = __builtin_amdgcn_mfma_f32_16x16x32_bf16(aq[0][0], bk0, s0, 0, 0, 0);
        s0 = __builtin_amdgcn_mfma_f32_16x16x32_bf16(aq[0][1], bk1, s0, 0, 0, 0);
        s1 = __builtin_amdgcn_mfma_f32_16x16x32_bf16(aq[1][0], bk0, s1, 0, 0, 0);
        s1 = __builtin_amdgcn_mfma_f32_16x16x32_bf16(aq[1][1], bk1, s1, 0, 0, 0);
      }
      const int kc  = kb + l15;
      const int row = i * 16 + l15;
#pragma unroll
      for (int mt = 0; mt < 2; ++mt) {
        f32x4 sv = (mt == 0) ? s0 : s1;
        float p4[4];
#pragma unroll
        for (int r = 0; r < 4; ++r) {
          const int qrow = q0 + mt * 16 + quad * 4 + r;
          float e;
          if (deg) {
            e = (kc <= qrow) ? 1.0f : 0.0f;
          } else {
            e = (kc < vlen && kc <= qrow) ? __expf(sv[r] * scale) : 0.0f;
          }
          lrun[mt][r] += e;
          p4[r] = e;
        }
        const int col = mt * 16 + quad * 4;
        *(uint32_t*)&Pt[w][row][col]     = pack2bf(p4[0], p4[1]);
        *(uint32_t*)&Pt[w][row][col + 2] = pack2bf(p4[2], p4[3]);
      }
    }

    // ---- 16-lane sum reduce; atomic add per-wave partials into Ls ----
#pragma unroll
    for (int mt = 0; mt < 2; ++mt)
#pragma unroll
      for (int r = 0; r < 4; ++r) {
        float l = lrun[mt][r];
#pragma unroll
        for (int off = 1; off < 16; off <<= 1) l += __shfl_xor(l, off, 64);
        lrun[mt][r] = l;
      }
    if (l15 == 0) {
#pragma unroll
      for (int mt = 0; mt < 2; ++mt)
#pragma unroll
        for (int r = 0; r < 4; ++r)
          atomicAdd(&Ls[mt * 16 + quad * 4 + r], lrun[mt][r]);
    }
    __syncthreads();   // B1: Pt + Vt-raw + complete Ls visible

    // ---- scale Vt rows by 1/L_q in place (rcp inline) ----
#pragma unroll
    for (int j = 0; j < 6; ++j) {
      const int idx = t + j * 256;      // 0..1535
      const int d = idx >> 5, q = idx & 31;
      float f = __uint_as_float((uint32_t)Vt[d][q] << 16) * (1.0f / Ls[q]);
      Vt[d][q] = f2bf(f);
    }
    __syncthreads();   // B2: scaled Vt visible

    if (t < 32) Ls[t] = 0.0f;   // reset for next iter (PV doesn't read Ls)

    // ---- PV MFMAs: Oacc[k_loc][d] += P^T[k][q] V'[q][d] ----
    bf16x8 bv[3];
#pragma unroll
    for (int dt = 0; dt < 3; ++dt)
      bv[dt] = lds_frag8(&Vt[dt * 16 + l15][quad * 8]);
#pragma unroll
    for (int i = 0; i < 8; ++i) {
      if (64 * i > lim) continue;
      bf16x8 ap = lds_frag8(&Pt[w][i * 16 + l15][quad * 8]);
#pragma unroll
      for (int dt = 0; dt < 3; ++dt)
        Oacc[i][dt] = __builtin_amdgcn_mfma_f32_16x16x32_bf16(
            ap, bv[dt], Oacc[i][dt], 0, 0, 0);
    }
  }

  // ---- epilogue: Q_len row mask, fp32 out [B][L][H*DH] ----
#pragma unroll
  for (int i = 0; i < 8; ++i) {
#pragma unroll
    for (int r = 0; r < 4; ++r) {
      const int k_abs = 64 * i + 16 * w + quad * 4 + r;
      const float msk = (k_abs < qlen) ? 1.0f : 0.0f;
      float* orow = out + (size_t)(b * L_ + k_abs) * DOUT_ + h * DH_;
#pragma unroll
      for (int dt = 0; dt < 3; ++dt)
        orow[dt * 16 + l15] = Oacc[i][dt][r] * msk;
    }
  }
}

// ---------------------------------------------------------------------------
// launch
// ---------------------------------------------------------------------------
extern "C" void kernel_launch(void* const* d_in, const int* in_sizes, int n_in,
                              void* d_out, int out_size, void* d_ws, size_t ws_size,
                              hipStream_t stream) {
  const float* Qs  = (const float*)d_in[0];
  const float* Kse = (const float*)d_in[1];
  const float* Vs  = (const float*)d_in[2];
  const float* WQ  = (const float*)d_in[3];
  const float* WK  = (const float*)d_in[4];
  const float* WV  = (const float*)d_in[5];
  const int*   Qlen = (const int*)d_in[6];
  const int*   Vlen = (const int*)d_in[7];
  float* out = (float*)d_out;

  char* ws = (char*)d_ws;
  int* lens = (int*)ws;
  uint16_t* qh = (uint16_t*)(ws + 256);
  uint16_t* kh = qh + (size_t)B_ * H_ * L_ * DH_;
  uint16_t* vh = kh + (size_t)B_ * H_ * L_ * DH_;
  uint16_t* Wt = vh + (size_t)B_ * H_ * L_ * DH_;

  lens_kernel<<<1, 64, 0, stream>>>(Qlen, Vlen, lens);
  wconv_kernel<<<dim3(3, 192, 3), 256, 0, stream>>>(WQ, WK, WV, Wt);
  mfma_proj<<<dim3(16384 / 128, DOUT_ / 128, 3), 512, 0, stream>>>(
      Qs, Kse, Vs, Wt, qh, kh, vh);
  attn_mfma<<<NHEADS, 256, 0, stream>>>(qh, kh, vh, lens, out);
}